// Round 9
// baseline (358.065 us; speedup 1.0000x reference)
//
#include <hip/hip_runtime.h>
#include <math.h>

// Problem constants (B,Cin,Ce,Ci,Cout,H,W,K) = (16,32,32,32,32,128,128,3)
#define BB 16
#define C  32
#define H  128
#define W  128

#define HE_OFF   ((size_t)BB*C*H*W)      // h_e_new at out + 8388608
#define HI_OFF   ((size_t)2*BB*C*H*W)    // h_i_new

// d_ws byte offsets. Weight block (~130 KB), then 3 fp16 NHWC tensors.
#define WSB_WA    0         // wpackA fp16 [s3][tap9][mt4][lane64][j8] = 110592 B
#define WSB_WO    110592    // wpackO fp16 [tap9][mt2][lane64][j8]    = 18432 B
#define WSB_BIAS  129024    // f32[64]  combined cand bias (e||i)
#define WSB_ITAU  129280    // f32[64]  1/max(tau,1) (e||i)
#define WSB_BOUT  129536    // f32[32]  relu(b_e_out)
#define WSB_F16   131072    // 3 fp16 NHWC tensors: x, h_e, h_i
#define TBYTES    16777216  // bytes per fp16 NHWC tensor
#define IMGB      1048576   // bytes per image

typedef _Float16 half8 __attribute__((ext_vector_type(8)));
typedef _Float16 half4 __attribute__((ext_vector_type(4)));
typedef float    f32x4 __attribute__((ext_vector_type(4)));

__device__ __forceinline__ float fast_tanh(float x) {
  float ax = fabsf(x);
  float e  = __expf(2.f * ax);
  float t  = 1.f - 2.f / (e + 1.f);
  return copysignf(t, x);
}

// ---------------- Kernel 0: weight/bias prepack (HW-verified layout) -----
__global__ void prep_kernel(const float* __restrict__ W_in_e, const float* __restrict__ b_in_e,
                            const float* __restrict__ W_in_i, const float* __restrict__ b_in_i,
                            const float* __restrict__ W_e_e,  const float* __restrict__ b_e_e,
                            const float* __restrict__ W_e_i,  const float* __restrict__ b_e_i,
                            const float* __restrict__ W_e_out,const float* __restrict__ b_e_out,
                            const float* __restrict__ W_i_e,  const float* __restrict__ b_i_e,
                            const float* __restrict__ W_i_i,  const float* __restrict__ b_i_i,
                            const float* __restrict__ tau_e,  const float* __restrict__ tau_i,
                            unsigned char* __restrict__ ws) {
  int t = blockIdx.x * 256 + threadIdx.x;
  _Float16* wa = (_Float16*)(ws + WSB_WA);
  _Float16* wo = (_Float16*)(ws + WSB_WO);
  float* bias64 = (float*)(ws + WSB_BIAS);
  float* itau64 = (float*)(ws + WSB_ITAU);
  float* bout   = (float*)(ws + WSB_BOUT);

  if (t < 55296) {
    int s = t / 18432, r1 = t % 18432;
    int tap = r1 / 2048, r2 = r1 % 2048;
    int mt = r2 / 512, r3 = r2 % 512;
    int lane = r3 >> 3, j = r3 & 7;
    int ch64 = mt*16 + (lane & 15);
    int cin  = (lane >> 4)*8 + j;
    int dy = tap / 3, dx = tap % 3;
    float v;
    if (ch64 < C) {
      int off = ((ch64*C + cin)*3 + dy)*3 + dx;
      v = (s==0) ? W_in_e[off] : (s==1) ? fmaxf(W_e_e[off],0.f) : -fmaxf(W_i_e[off],0.f);
    } else {
      int off = (((ch64-C)*C + cin)*3 + dy)*3 + dx;
      v = (s==0) ? W_in_i[off] : (s==1) ? fmaxf(W_e_i[off],0.f) : -fmaxf(W_i_i[off],0.f);
    }
    wa[t] = (_Float16)v;
  }
  if (t < 9216) {
    int tap = t / 1024, r2 = t % 1024;
    int mt = r2 / 512, r3 = r2 % 512;
    int lane = r3 >> 3, j = r3 & 7;
    int ch  = mt*16 + (lane & 15);
    int cin = (lane >> 4)*8 + j;
    int dy = tap / 3, dx = tap % 3;
    wo[t] = (_Float16)fmaxf(W_e_out[((ch*C + cin)*3 + dy)*3 + dx], 0.f);
  }
  if (t < 64) {
    if (t < 32) {
      bias64[t] = b_in_e[t] + fmaxf(b_e_e[t],0.f) - fmaxf(b_i_e[t],0.f);
      itau64[t] = 1.f / fmaxf(tau_e[t], 1.f);
      bout[t]   = fmaxf(b_e_out[t], 0.f);
    } else {
      bias64[t] = b_in_i[t-32] + fmaxf(b_e_i[t-32],0.f) - fmaxf(b_i_i[t-32],0.f);
      itau64[t] = 1.f / fmaxf(tau_i[t-32], 1.f);
    }
  }
}

// ---------------- Kernel 0b: fp32 NCHW -> fp16 NHWC convert ---------------
__global__ __launch_bounds__(128) void convert_kernel(
    const float* __restrict__ x, const float* __restrict__ he,
    const float* __restrict__ hi, unsigned char* __restrict__ ws) {
  const int bid = blockIdx.x;
  const int b = bid >> 7, y = bid & 127;
  const int lane = threadIdx.x;
  const float* srcs[3] = {x, he, hi};
  #pragma unroll
  for (int t = 0; t < 3; ++t) {
    const float* src = srcs[t] + (size_t)b*C*H*W + (size_t)y*W + lane;
    _Float16* dst = (_Float16*)(ws + WSB_F16 + (size_t)t*TBYTES)
                    + (size_t)b*(C*H*W) + ((size_t)y*W + lane)*C;
    half8 o[4];
    #pragma unroll
    for (int c = 0; c < 32; ++c)
      o[c>>3][c&7] = (_Float16)src[(size_t)c*H*W];
    #pragma unroll
    for (int k = 0; k < 4; ++k) *((half8*)dst + k) = o[k];
  }
}

// ---------------- fused kernel: cand(18x18) + state + out conv -----------
// Block = 256 thr (4 waves), one 16x16 output tile.
// buf0: [20][20][32] fp16 stages x then h_i; buf1: h_e then h_e_new in-place.
// cand computed on 18x18 halo (324 px, n-tiles mix rows: GEMM cols indep);
// out conv consumes h_e_new straight from LDS.
__device__ __forceinline__ void stage20(const unsigned char* __restrict__ src,
                                        _Float16* buf, int ty0, int tx0, int tid) {
  for (int i = tid; i < 1600; i += 256) {   // 20*20*4 16B chunks
    int yy = i / 80, rem = i % 80;
    int xx = rem >> 2, k = rem & 3;
    int gr = ty0 - 2 + yy, gc = tx0 - 2 + xx;
    half8 v;
    #pragma unroll
    for (int j = 0; j < 8; ++j) v[j] = (_Float16)0.f;
    if ((unsigned)gr < H && (unsigned)gc < W)
      v = *(const half8*)(src + (gr*W + gc)*64 + k*16);
    *(half8*)((char*)buf + (yy*20 + xx)*64 + ((k ^ ((xx>>1)&3)) << 4)) = v;
  }
}

#define CAND_MFMA(BUFP, WPTR) do {                                            \
  _Pragma("unroll") for (int dy = 0; dy < 3; ++dy) {                          \
    _Pragma("unroll") for (int dx = 0; dx < 3; ++dx) {                        \
      const int tap = dy*3 + dx;                                              \
      half8 bf[6];                                                            \
      _Pragma("unroll") for (int nt = 0; nt < 6; ++nt) {                      \
        if (nt < NTE) {                                                       \
          int rr = pr[nt] + dy, cc = pc[nt] + dx;                             \
          bf[nt] = *(const half8*)((const char*)(BUFP) + (rr*20 + cc)*64      \
                                   + ((q ^ ((cc>>1)&3)) << 4));               \
        }                                                                     \
      }                                                                       \
      _Pragma("unroll") for (int mt = 0; mt < 4; ++mt) {                      \
        half8 af = *(const half8*)((WPTR) + ((tap*4 + mt)*64 + l)*16);        \
        _Pragma("unroll") for (int nt = 0; nt < 6; ++nt)                      \
          if (nt < NTE)                                                       \
            acc[mt][nt] = __builtin_amdgcn_mfma_f32_16x16x32_f16(             \
                af, bf[nt], acc[mt][nt], 0, 0, 0);                            \
      }                                                                       \
    }                                                                         \
  }                                                                           \
} while (0)

__global__ __launch_bounds__(256, 2) void fused_kernel(
    const unsigned char* __restrict__ ws, float* __restrict__ out) {
  __shared__ _Float16 buf0[12800];   // 25,600 B
  __shared__ _Float16 buf1[12800];   // 25,600 B -> total 51.2 KB

  const int b   = blockIdx.z;
  const int ty0 = blockIdx.y * 16, tx0 = blockIdx.x * 16;
  const int tid = threadIdx.x;
  const int wid = tid >> 6, l = tid & 63;
  const int q   = l >> 4, xl = l & 15;

  // per-lane pixel coords for the 18x18 cand region; ntile = nt*4 + wid
  int pr[6], pc[6];
  #pragma unroll
  for (int nt = 0; nt < 6; ++nt) {
    int px = (nt*4 + wid)*16 + xl;
    int v  = px < 324 ? px : 323;
    pr[nt] = v / 18;
    pc[nt] = v - pr[nt]*18;
  }
  const int NTE = (wid == 0) ? 6 : 5;   // tiles 21..23 are empty

  const float* bias64 = (const float*)(ws + WSB_BIAS);
  const float* itau64 = (const float*)(ws + WSB_ITAU);

  f32x4 acc[4][6];
  #pragma unroll
  for (int mt = 0; mt < 4; ++mt) {
    f32x4 bv = *(const f32x4*)(bias64 + mt*16 + q*4);
    #pragma unroll
    for (int nt = 0; nt < 6; ++nt) acc[mt][nt] = bv;
  }

  const unsigned char* t16 = ws + WSB_F16 + (size_t)b*IMGB;
  stage20(t16 + 0*(size_t)TBYTES, buf0, ty0, tx0, tid);   // x
  stage20(t16 + 1*(size_t)TBYTES, buf1, ty0, tx0, tid);   // h_e
  __syncthreads();
  CAND_MFMA(buf0, ws + WSB_WA + 0*36864);
  CAND_MFMA(buf1, ws + WSB_WA + 1*36864);
  __syncthreads();                                        // x reads done
  stage20(t16 + 2*(size_t)TBYTES, buf0, ty0, tx0, tid);   // h_i over x
  __syncthreads();
  CAND_MFMA(buf0, ws + WSB_WA + 2*36864);

  // ---- epilogue 1: tanh + leaky integration; h_e_new -> buf1 in place ----
  #pragma unroll
  for (int mt = 0; mt < 4; ++mt) {
    f32x4 tv = *(const f32x4*)(itau64 + mt*16 + q*4);
    const int chb  = (mt & 1)*16 + q*4;        // channel base in population
    const int klog = (mt & 1)*2 + (q >> 1);    // 16B chunk of chb..chb+3
    _Float16* hbuf = (mt < 2) ? buf1 : buf0;   // old h_e : old h_i
    float* dst32 = out + ((mt < 2) ? HE_OFF : HI_OFF);
    #pragma unroll
    for (int nt = 0; nt < 6; ++nt) {
      if (nt < NTE) {
        int px = (nt*4 + wid)*16 + xl;
        bool pxv = px < 324;
        int r = pr[nt], c = pc[nt];
        int gy = ty0 - 1 + r, gx = tx0 - 1 + c;
        bool inimg = ((unsigned)gy < H) && ((unsigned)gx < W);
        bool interior = (r >= 1) && (r < 17) && (c >= 1) && (c < 17);
        int slot  = ((r + 1)*20 + (c + 1))*64;
        int kphys = klog ^ (((c + 1) >> 1) & 3);
        half4 hold = *(const half4*)((const char*)hbuf + slot + kphys*16 + (q & 1)*8);
        float res[4];
        #pragma unroll
        for (int rr = 0; rr < 4; ++rr) {
          float it = tv[rr];
          res[rr] = (1.f - it)*(float)hold[rr] + it*fast_tanh(acc[mt][nt][rr]);
        }
        if (mt < 2 && pxv) {                   // h_e_new fp16 into buf1 (0 = SAME pad)
          half4 h16;
          #pragma unroll
          for (int rr = 0; rr < 4; ++rr)
            h16[rr] = inimg ? (_Float16)res[rr] : (_Float16)0.f;
          *(half4*)((char*)buf1 + slot + kphys*16 + (q & 1)*8) = h16;
        }
        if (pxv && interior) {
          #pragma unroll
          for (int rr = 0; rr < 4; ++rr)
            dst32[(((size_t)b*C + (chb + rr))*H + gy)*W + gx] = res[rr];
        }
      }
    }
  }
  __syncthreads();                              // h_e_new complete in buf1

  // ---- out conv: 16x16 interior from buf1 (h_e_new) ----
  const unsigned char* wo = ws + WSB_WO;
  const float* bout = (const float*)(ws + WSB_BOUT);
  f32x4 ao[2][4];
  #pragma unroll
  for (int mt = 0; mt < 2; ++mt) {
    f32x4 bv = *(const f32x4*)(bout + mt*16 + q*4);
    #pragma unroll
    for (int nt = 0; nt < 4; ++nt) ao[mt][nt] = bv;
  }
  #pragma unroll
  for (int dy = 0; dy < 3; ++dy) {
    #pragma unroll
    for (int dx = 0; dx < 3; ++dx) {
      const int tap = dy*3 + dx;
      half8 bf[4];
      #pragma unroll
      for (int nt = 0; nt < 4; ++nt) {
        int px = (nt*4 + wid)*16 + xl;
        int ti = (px >> 4) + dy + 1, tj = (px & 15) + dx + 1;
        bf[nt] = *(const half8*)((const char*)buf1 + (ti*20 + tj)*64
                                 + ((q ^ ((tj>>1)&3)) << 4));
      }
      #pragma unroll
      for (int mt = 0; mt < 2; ++mt) {
        half8 af = *(const half8*)(wo + ((tap*2 + mt)*64 + l)*16);
        #pragma unroll
        for (int nt = 0; nt < 4; ++nt)
          ao[mt][nt] = __builtin_amdgcn_mfma_f32_16x16x32_f16(af, bf[nt], ao[mt][nt], 0, 0, 0);
      }
    }
  }
  #pragma unroll
  for (int mt = 0; mt < 2; ++mt) {
    #pragma unroll
    for (int nt = 0; nt < 4; ++nt) {
      int px = (nt*4 + wid)*16 + xl;
      int gy = ty0 + (px >> 4), gx = tx0 + (px & 15);
      #pragma unroll
      for (int rr = 0; rr < 4; ++rr) {
        int ch = mt*16 + q*4 + rr;
        out[(((size_t)b*C + ch)*H + gy)*W + gx] = fast_tanh(ao[mt][nt][rr]);
      }
    }
  }
}

// ---------------- launch --------------------------------------------------
extern "C" void kernel_launch(void* const* d_in, const int* in_sizes, int n_in,
                              void* d_out, int out_size, void* d_ws, size_t ws_size,
                              hipStream_t stream) {
  const float* x      = (const float*)d_in[0];
  const float* h_e    = (const float*)d_in[1];
  const float* h_i    = (const float*)d_in[2];
  const float* W_in_e = (const float*)d_in[3];
  const float* b_in_e = (const float*)d_in[4];
  const float* W_in_i = (const float*)d_in[5];
  const float* b_in_i = (const float*)d_in[6];
  const float* W_e_e  = (const float*)d_in[7];
  const float* b_e_e  = (const float*)d_in[8];
  const float* W_e_i  = (const float*)d_in[9];
  const float* b_e_i  = (const float*)d_in[10];
  const float* W_e_out= (const float*)d_in[11];
  const float* b_e_out= (const float*)d_in[12];
  const float* W_i_e  = (const float*)d_in[13];
  const float* b_i_e  = (const float*)d_in[14];
  const float* W_i_i  = (const float*)d_in[15];
  const float* b_i_i  = (const float*)d_in[16];
  const float* tau_e  = (const float*)d_in[17];
  const float* tau_i  = (const float*)d_in[18];

  unsigned char* ws = (unsigned char*)d_ws;
  float* out = (float*)d_out;

  prep_kernel<<<216, 256, 0, stream>>>(W_in_e, b_in_e, W_in_i, b_in_i,
                                       W_e_e, b_e_e, W_e_i, b_e_i,
                                       W_e_out, b_e_out, W_i_e, b_i_e,
                                       W_i_i, b_i_i, tau_e, tau_i, ws);

  convert_kernel<<<BB*H, 128, 0, stream>>>(x, h_e, h_i, ws);

  dim3 grid(W/16, H/16, BB);   // 8 x 8 x 16 = 1024 blocks
  fused_kernel<<<grid, 256, 0, stream>>>(ws, out);
}